// Round 1
// baseline (197.745 us; speedup 1.0000x reference)
//
#include <hip/hip_runtime.h>

// Problem shape (fixed by reference): N=64, C=1024, H=W=28 -> HW=784
#define HWD 784
#define CD  1024
#define ND  64

// ---------------------------------------------------------------------------
// Kernel 1: thr[n,c] = mu * max_{hw} relu(x[n,c,hw] * w[c])
// One wave (64 lanes) per (n,c). 4 waves / 256-thread block.
// ---------------------------------------------------------------------------
__global__ void __launch_bounds__(256) thr_kernel(const float* __restrict__ x,
                                                  const float* __restrict__ w,
                                                  const float* __restrict__ mu_p,
                                                  float* __restrict__ thr) {
    const int wave = threadIdx.x >> 6;
    const int lane = threadIdx.x & 63;
    const int nc = blockIdx.x * 4 + wave;   // 0 .. N*C-1
    const int c = nc & (CD - 1);
    const float wc = w[c];

    const float4* row = reinterpret_cast<const float4*>(x + (size_t)nc * HWD);
    float m = 0.0f;  // relu lower bound is 0, so starting at 0 implements relu
    // HWD/4 = 196 float4 per row; lanes stride by 64 -> 4 iters for lanes 0..3
    for (int i = lane; i < HWD / 4; i += 64) {
        float4 v = row[i];
        m = fmaxf(m, v.x * wc);
        m = fmaxf(m, v.y * wc);
        m = fmaxf(m, v.z * wc);
        m = fmaxf(m, v.w * wc);
    }
    // wave(64)-wide max reduction
    #pragma unroll
    for (int off = 32; off > 0; off >>= 1)
        m = fmaxf(m, __shfl_xor(m, off, 64));

    if (lane == 0)
        thr[nc] = m * mu_p[0];
}

// ---------------------------------------------------------------------------
// Kernel 2: S[n,pos] = sum_c (cam > thr[n,c] ? 0 : cam),  cam = relu(x*w)
// One thread per (n,pos). Wave reads 64 consecutive floats per c iteration.
// ---------------------------------------------------------------------------
__global__ void __launch_bounds__(256) sum_kernel(const float* __restrict__ x,
                                                  const float* __restrict__ w,
                                                  const float* __restrict__ thr,
                                                  float* __restrict__ S) {
    const int gid = blockIdx.x * 256 + threadIdx.x;   // 0 .. N*HWD-1 (50176)
    const int n = gid / HWD;
    const int pos = gid - n * HWD;
    const float* base = x + (size_t)n * CD * HWD + pos;
    const float* thr_n = thr + n * CD;

    float s = 0.0f;
    #pragma unroll 4
    for (int c = 0; c < CD; ++c) {
        float v = base[(size_t)c * HWD];
        float cam = fmaxf(v * w[c], 0.0f);
        s += (cam > thr_n[c]) ? 0.0f : cam;
    }
    S[gid] = s;
}

// ---------------------------------------------------------------------------
// Kernel 3: out[n,c,pos] = x[n,c,pos] * S[n,pos]   (float4 elementwise)
// ---------------------------------------------------------------------------
__global__ void __launch_bounds__(256) out_kernel(const float* __restrict__ x,
                                                  const float* __restrict__ S,
                                                  float* __restrict__ out) {
    const int i4 = blockIdx.x * 256 + threadIdx.x;    // 0 .. N*C*HWD/4-1
    const int q = i4 / (HWD / 4);                     // nc index
    const int pos4 = i4 - q * (HWD / 4);
    const int n = q >> 10;                            // / CD

    float4 xv = reinterpret_cast<const float4*>(x)[i4];
    float4 sv = reinterpret_cast<const float4*>(S + (size_t)n * HWD)[pos4];
    float4 o;
    o.x = xv.x * sv.x;
    o.y = xv.y * sv.y;
    o.z = xv.z * sv.z;
    o.w = xv.w * sv.w;
    reinterpret_cast<float4*>(out)[i4] = o;
}

extern "C" void kernel_launch(void* const* d_in, const int* in_sizes, int n_in,
                              void* d_out, int out_size, void* d_ws, size_t ws_size,
                              hipStream_t stream) {
    const float* x  = (const float*)d_in[0];   // [N, C, H, W] f32
    const float* w  = (const float*)d_in[1];   // [C] f32
    const float* mu = (const float*)d_in[2];   // scalar (1-elem array)
    float* out = (float*)d_out;

    float* thr = (float*)d_ws;                          // N*C floats   (256 KB)
    float* S   = thr + (size_t)ND * CD;                 // N*HWD floats (200 KB)

    // Kernel 1: N*C = 65536 waves, 4 per block -> 16384 blocks
    thr_kernel<<<(ND * CD) / 4, 256, 0, stream>>>(x, w, mu, thr);

    // Kernel 2: N*HWD = 50176 threads -> 196 blocks
    sum_kernel<<<(ND * HWD) / 256, 256, 0, stream>>>(x, w, thr, S);

    // Kernel 3: N*C*HWD/4 = 12845056 float4 -> 50176 blocks
    out_kernel<<<(ND * CD * HWD / 4) / 256, 256, 0, stream>>>(x, S, out);
}

// Round 2
// 178.615 us; speedup vs baseline: 1.1071x; 1.1071x over previous
//
#include <hip/hip_runtime.h>

// Problem shape (fixed by reference): N=64, C=1024, H=W=28 -> HW=784
#define HWD 784
#define CD  1024
#define ND  64

#define TILE 56            // positions per block (784 = 14*56); 224B segments
#define NTILE (HWD / TILE) // 14
#define PG 4               // channel groups in phase A
#define CPT (CD / PG)      // 256 channels per phase-A thread

// ---------------------------------------------------------------------------
// Kernel 1: thr[n,c] = mu * max_{hw} relu(x[n,c,hw] * w[c])
// One wave (64 lanes) per (n,c). 4 waves / 256-thread block.
// ---------------------------------------------------------------------------
__global__ void __launch_bounds__(256) thr_kernel(const float* __restrict__ x,
                                                  const float* __restrict__ w,
                                                  const float* __restrict__ mu_p,
                                                  float* __restrict__ thr) {
    const int wave = threadIdx.x >> 6;
    const int lane = threadIdx.x & 63;
    const int nc = blockIdx.x * 4 + wave;   // 0 .. N*C-1
    const int c = nc & (CD - 1);
    const float wc = w[c];

    const float4* row = reinterpret_cast<const float4*>(x + (size_t)nc * HWD);
    float m = 0.0f;  // relu lower bound is 0, so starting at 0 implements relu
    for (int i = lane; i < HWD / 4; i += 64) {   // 196 float4 per row
        float4 v = row[i];
        m = fmaxf(m, v.x * wc);
        m = fmaxf(m, v.y * wc);
        m = fmaxf(m, v.z * wc);
        m = fmaxf(m, v.w * wc);
    }
    #pragma unroll
    for (int off = 32; off > 0; off >>= 1)
        m = fmaxf(m, __shfl_xor(m, off, 64));

    if (lane == 0)
        thr[nc] = m * mu_p[0];
}

// ---------------------------------------------------------------------------
// Fused kernel 2+3: per block = (n, tile of 56 positions)
//   Phase A: S[p] = sum_c (cam > thr ? 0 : cam) over all 1024 channels
//   Phase B: out[n,c,pos] = x[n,c,pos] * S[pos]   (re-read is L2/L3-hot)
// ---------------------------------------------------------------------------
__global__ void __launch_bounds__(256) fused_kernel(const float* __restrict__ x,
                                                    const float* __restrict__ w,
                                                    const float* __restrict__ thr,
                                                    float* __restrict__ out) {
    __shared__ float w_s[CD];
    __shared__ float thr_s[CD];
    __shared__ float part[PG][TILE];
    __shared__ float S_s[TILE];

    const int t = threadIdx.x;
    const int n = blockIdx.y;
    const int pos0 = blockIdx.x * TILE;
    const size_t nbase = (size_t)n * CD * HWD;

    // stage w and thr[n,:] in LDS (broadcast reads in phase A)
    const float* thr_n = thr + n * CD;
    #pragma unroll
    for (int i = 0; i < CD / 256; ++i) {
        w_s[t + 256 * i]   = w[t + 256 * i];
        thr_s[t + 256 * i] = thr_n[t + 256 * i];
    }
    __syncthreads();

    // ---- Phase A: dropped-sum over channels, 4 groups x 56 positions ----
    if (t < PG * TILE) {                 // 224 active threads
        const int g = t / TILE;          // 0..3 channel group
        const int p = t - g * TILE;      // 0..55 position in tile
        const float* base = x + nbase + pos0 + p;
        float s = 0.0f;
        #pragma unroll 8
        for (int k = 0; k < CPT; ++k) {
            const int c = g + k * PG;
            float v = base[(size_t)c * HWD];
            float cam = fmaxf(v * w_s[c], 0.0f);
            s += (cam > thr_s[c]) ? 0.0f : cam;
        }
        part[g][p] = s;
    }
    __syncthreads();
    if (t < TILE)
        S_s[t] = part[0][t] + part[1][t] + part[2][t] + part[3][t];
    __syncthreads();

    // ---- Phase B: out = x * S, float4, 224B-contiguous per channel row ----
    const int QT = TILE / 4;             // 14 float4 per channel row
    for (int j = t; j < CD * QT; j += 256) {   // 56 iterations
        const int c = j / QT;
        const int q = j - c * QT;
        const size_t idx = nbase + (size_t)c * HWD + pos0 + q * 4;
        float4 xv = *reinterpret_cast<const float4*>(x + idx);
        float4 sv = *reinterpret_cast<const float4*>(S_s + q * 4);
        float4 o;
        o.x = xv.x * sv.x;
        o.y = xv.y * sv.y;
        o.z = xv.z * sv.z;
        o.w = xv.w * sv.w;
        *reinterpret_cast<float4*>(out + idx) = o;
    }
}

extern "C" void kernel_launch(void* const* d_in, const int* in_sizes, int n_in,
                              void* d_out, int out_size, void* d_ws, size_t ws_size,
                              hipStream_t stream) {
    const float* x  = (const float*)d_in[0];   // [N, C, H, W] f32
    const float* w  = (const float*)d_in[1];   // [C] f32
    const float* mu = (const float*)d_in[2];   // scalar (1-elem array)
    float* out = (float*)d_out;

    float* thr = (float*)d_ws;                 // N*C floats (256 KB scratch)

    // Kernel 1: N*C = 65536 waves, 4 per block -> 16384 blocks
    thr_kernel<<<(ND * CD) / 4, 256, 0, stream>>>(x, w, mu, thr);

    // Fused kernel: 14 x 64 = 896 blocks
    dim3 g2(NTILE, ND);
    fused_kernel<<<g2, 256, 0, stream>>>(x, w, thr, out);
}